// Round 4
// baseline (569.434 us; speedup 1.0000x reference)
//
#include <hip/hip_runtime.h>
#include <math.h>

typedef unsigned short u16;
typedef unsigned short u16x8 __attribute__((ext_vector_type(8)));
typedef unsigned short u16x4 __attribute__((ext_vector_type(4)));
typedef _Float16 f16x8 __attribute__((ext_vector_type(8)));
typedef float f32x4 __attribute__((ext_vector_type(4)));

#define LOG2E 1.4426950408889634f

static __device__ __forceinline__ u16 f2h(float f) { return __builtin_bit_cast(u16, (_Float16)f); }
static __device__ __forceinline__ float h2f(u16 u) { return (float)__builtin_bit_cast(_Float16, u); }

// async global->LDS, 16B per lane; LDS dest = wave-uniform base + lane*16
static __device__ __forceinline__ void g2l16(const u16* g, u16* l) {
    __builtin_amdgcn_global_load_lds(
        (const __attribute__((address_space(1))) void*)g,
        (__attribute__((address_space(3))) void*)l, 16, 0, 0);
}

static __device__ __forceinline__ u16x8 ld8f(const float* p) {
    f32x4 a = *(const f32x4*)p;
    f32x4 b = *(const f32x4*)(p + 4);
    u16x8 r;
    r[0] = f2h(a[0]); r[1] = f2h(a[1]); r[2] = f2h(a[2]); r[3] = f2h(a[3]);
    r[4] = f2h(b[0]); r[5] = f2h(b[1]); r[6] = f2h(b[2]); r[7] = f2h(b[3]);
    return r;
}

// ---------------------------------------------------------------------------
// fused fp32->f16 convert: hs (4096 blk) + Wq + Wk + Wv (2048 blk each)
// ---------------------------------------------------------------------------
__global__ __launch_bounds__(256) void cvt4(
    const float* __restrict__ hs, const float* __restrict__ Wq,
    const float* __restrict__ Wk, const float* __restrict__ Wv,
    u16* __restrict__ hs16, u16* __restrict__ wq16,
    u16* __restrict__ wk16, u16* __restrict__ wv16)
{
    int blk = blockIdx.x;
    const float* s; u16* d;
    if (blk < 4096)      { s = hs; d = hs16; }
    else if (blk < 6144) { s = Wq; d = wq16; blk -= 4096; }
    else if (blk < 8192) { s = Wk; d = wk16; blk -= 6144; }
    else                 { s = Wv; d = wv16; blk -= 8192; }
    const size_t e = ((size_t)blk * 256 + threadIdx.x) * 8;
    *(u16x8*)(d + e) = ld8f(s + e);
}

__global__ __launch_bounds__(256) void cvt1(const float* __restrict__ s, u16* __restrict__ d) {
    const size_t e = ((size_t)blockIdx.x * 256 + threadIdx.x) * 8;
    *(u16x8*)(d + e) = ld8f(s + e);
}

// ---------------------------------------------------------------------------
// QKV GEMM v3: fragment-major LDS. Slot (group g, lane l) holds
// A[16g + (l&15)][kt + (l>>4)*8 ..+8]; fragment read = base + l*16 (linear,
// conflict-free, imm-offset addressing). Triple-buffered counted-vmcnt
// schedule unchanged from v2. z=0->Q, 1->K; z=2->V^T [b,h,d,s].
// ---------------------------------------------------------------------------
__global__ __launch_bounds__(256, 4) void gemm_qkv(
    const u16* __restrict__ A,
    const u16* __restrict__ W0, const u16* __restrict__ W1, const u16* __restrict__ W2,
    const float* __restrict__ B0, const float* __restrict__ B1, const float* __restrict__ B2,
    u16* __restrict__ Cq, u16* __restrict__ Ck, u16* __restrict__ Cvt)
{
    constexpr int K = 2048, N = 2048, NT = K / 32;
    const int z = blockIdx.z;
    const u16* W      = (z == 0) ? W0 : ((z == 1) ? W1 : W2);
    const float* bias = (z == 0) ? B0 : ((z == 1) ? B1 : B2);
    const int m0 = blockIdx.y * 128, n0 = blockIdx.x * 128;

    // 8 groups x 512 u16 (1KB) per buffer, 3 buffers
    __shared__ __attribute__((aligned(16))) u16 As[3][8 * 512];
    __shared__ __attribute__((aligned(16))) u16 Bs[3][8 * 512];

    const int tid = threadIdx.x, l = tid & 63, w = tid >> 6;
    const int quad = l >> 4, lan = l & 15;

    // staging: wave w fills groups {2w, 2w+1} of As and Bs.
    // group g source: row = 16g + (l&15), k-chunk = (l>>4)*8
    const u16* pA0 = A + (size_t)(m0 + 32 * w + lan) * K + quad * 8;
    const u16* pA1 = A + (size_t)(m0 + 32 * w + 16 + lan) * K + quad * 8;
    const u16* pB0 = W + (size_t)(n0 + 32 * w + lan) * K + quad * 8;
    const u16* pB1 = W + (size_t)(n0 + 32 * w + 16 + lan) * K + quad * 8;
    const int dG0 = (2 * w) * 512;
    const int dG1 = (2 * w + 1) * 512;

    const int wm = (w >> 1) * 64, wn = (w & 1) * 64;
    const int ga0 = (w >> 1) * 4;    // A-groups ga0..ga0+3
    const int gb0 = (w & 1) * 4;     // B-groups gb0..gb0+3

    f32x4 acc[4][4] = {};

    // prologue: tiles 0 and 1 in flight; wait tile 0 (leave tile 1's 4 loads)
    {
        g2l16(pA0, &As[0][dG0]); g2l16(pA1, &As[0][dG1]);
        g2l16(pB0, &Bs[0][dG0]); g2l16(pB1, &Bs[0][dG1]);
        g2l16(pA0 + 32, &As[1][dG0]); g2l16(pA1 + 32, &As[1][dG1]);
        g2l16(pB0 + 32, &Bs[1][dG0]); g2l16(pB1 + 32, &Bs[1][dG1]);
    }
    __asm__ volatile("s_waitcnt vmcnt(4)" ::: "memory");
    __builtin_amdgcn_s_barrier();
    __builtin_amdgcn_sched_barrier(0);

    int bc = 0;
    for (int t = 0; t < NT; ++t) {
        int bi = bc + 2; if (bi >= 3) bi -= 3;
        if (t + 2 < NT) {
            const int kk = (t + 2) * 32;
            g2l16(pA0 + kk, &As[bi][dG0]); g2l16(pA1 + kk, &As[bi][dG1]);
            g2l16(pB0 + kk, &Bs[bi][dG0]); g2l16(pB1 + kk, &Bs[bi][dG1]);
        }

        const u16* Ab = As[bc];
        const u16* Bb = Bs[bc];
        f16x8 af[4], bf[4];
#pragma unroll
        for (int i = 0; i < 4; i++)
            af[i] = __builtin_bit_cast(f16x8, *(const u16x8*)(&Ab[((ga0 + i) * 64 + l) * 8]));
#pragma unroll
        for (int j = 0; j < 4; j++)
            bf[j] = __builtin_bit_cast(f16x8, *(const u16x8*)(&Bb[((gb0 + j) * 64 + l) * 8]));

        __builtin_amdgcn_s_setprio(1);
#pragma unroll
        for (int i = 0; i < 4; i++)
#pragma unroll
            for (int j = 0; j < 4; j++)
                acc[i][j] = __builtin_amdgcn_mfma_f32_16x16x32_f16(af[i], bf[j], acc[i][j], 0, 0, 0);
        __builtin_amdgcn_s_setprio(0);

        if (t + 1 < NT) {
            if (t + 2 < NT) { __asm__ volatile("s_waitcnt vmcnt(4)" ::: "memory"); }
            else            { __asm__ volatile("s_waitcnt vmcnt(0)" ::: "memory"); }
            __builtin_amdgcn_s_barrier();
            __builtin_amdgcn_sched_barrier(0);
        }
        bc = (bc == 2) ? 0 : bc + 1;
    }

    if (z < 2) {
        u16* C = (z == 0) ? Cq : Ck;
#pragma unroll
        for (int j = 0; j < 4; j++) {
            const int col = n0 + wn + j * 16 + lan;
            const float bj = bias[col];
#pragma unroll
            for (int i = 0; i < 4; i++)
#pragma unroll
                for (int r = 0; r < 4; r++) {
                    const int row = m0 + wm + i * 16 + quad * 4 + r;
                    C[(size_t)row * N + col] = f2h(acc[i][j][r] + bj);
                }
        }
    } else {
        // V transposed: row=(b,s), col=(h,d) -> Cvt[((b*16+h)*128+d)*2048 + s]
#pragma unroll
        for (int j = 0; j < 4; j++) {
            const int col = n0 + wn + j * 16 + lan;
            const int hh = col >> 7, dd = col & 127;
            const float bj = bias[col];
            u16* Cr = Cvt + ((size_t)hh * 128 + dd) * 2048;
#pragma unroll
            for (int i = 0; i < 4; i++) {
                const int row0 = m0 + wm + i * 16 + quad * 4;
                const int bb = row0 >> 11, ss = row0 & 2047;
                u16x4 pv;
#pragma unroll
                for (int r = 0; r < 4; r++) pv[r] = f2h(acc[i][j][r] + bj);
                *(u16x4*)(Cr + (size_t)bb * 4194304 + ss) = pv;
            }
        }
    }
}

// ---------------------------------------------------------------------------
// RMSNorm + RoPE + history key scale; in-place f16 q/k; q *= 1/sqrt(128).
// ---------------------------------------------------------------------------
__global__ __launch_bounds__(256) void norm_rope(
    u16* __restrict__ q, u16* __restrict__ k,
    const float* __restrict__ rot,
    const float* __restrict__ nqw, const float* __restrict__ nkw,
    const float* __restrict__ hks, const int* __restrict__ oclp)
{
    const int row = blockIdx.x;
    const int s = row & 2047;
    const int t = threadIdx.x;
    const size_t base = (size_t)row * 2048 + t * 8;

    u16x8 q8 = *(const u16x8*)(q + base);
    u16x8 k8 = *(const u16x8*)(k + base);

    float qf[8], kf[8];
    float sq = 0.f, sk = 0.f;
#pragma unroll
    for (int i = 0; i < 8; i++) {
        qf[i] = h2f(q8[i]); sq += qf[i] * qf[i];
        kf[i] = h2f(k8[i]); sk += kf[i] * kf[i];
    }
#pragma unroll
    for (int off = 32; off > 0; off >>= 1) {
        sq += __shfl_down(sq, off);
        sk += __shfl_down(sk, off);
    }
    __shared__ float rq[4], rk[4];
    const int wv = t >> 6;
    if ((t & 63) == 0) { rq[wv] = sq; rk[wv] = sk; }
    __syncthreads();
    const float tq = rq[0] + rq[1] + rq[2] + rq[3];
    const float tk = rk[0] + rk[1] + rk[2] + rk[3];
    const float scq = rsqrtf(tq * (1.0f / 2048.0f) + 1e-5f);
    const float sck = rsqrtf(tk * (1.0f / 2048.0f) + 1e-5f);
#pragma unroll
    for (int i = 0; i < 8; i++) {
        qf[i] *= scq * nqw[t * 8 + i];
        kf[i] *= sck * nkw[t * 8 + i];
    }
    const int e0 = t * 8;
    const int dh0 = e0 & 127;
    const int h = e0 >> 7;
    float qo[8], ko[8];
#pragma unroll
    for (int p = 0; p < 4; p++) {
        const int dh = dh0 + 2 * p;
        const float c  = rot[s * 256 + dh];
        const float sn = rot[s * 256 + 128 + dh + 1];
        qo[2 * p]     = qf[2 * p] * c  - qf[2 * p + 1] * sn;
        qo[2 * p + 1] = qf[2 * p] * sn + qf[2 * p + 1] * c;
        ko[2 * p]     = kf[2 * p] * c  - kf[2 * p + 1] * sn;
        ko[2 * p + 1] = kf[2 * p] * sn + kf[2 * p + 1] * c;
    }
    const float ATT = 0.08838834764831845f;
#pragma unroll
    for (int i = 0; i < 8; i++) qo[i] *= ATT;

    const int hist = 2048 - oclp[0];
    if (s < hist) {
        const float hv = hks[h];
        const float scl = 1.0f + 9.0f / (1.0f + expf(-hv));
#pragma unroll
        for (int i = 0; i < 8; i++) ko[i] *= scl;
    }

    u16x8 qo8, ko8;
#pragma unroll
    for (int i = 0; i < 8; i++) { qo8[i] = f2h(qo[i]); ko8[i] = f2h(ko[i]); }
    *(u16x8*)(q + base) = qo8;
    *(u16x8*)(k + base) = ko8;
}

// ---------------------------------------------------------------------------
// Flash attention v7: v6 + fragment-major K / V^T LDS.
// K slot (gk = nt*4+ks, l) = K[kv = nt*16 + (l&15)][d = ks*32 + (l>>4)*8];
// VT slot (nd, l)          = VT[d = nd*16 + (l&15)][kv = (l>>4)*8 ..].
// All kb/vtf reads are base + l*16 (conflict-free, imm offsets).
// 32 q-rows/wave (2 q-groups), QBLK=128/block, grid 16x32.
// LDS = 16(K) + 16(VT) + 10(P) = 42 KB -> 3 blocks/CU.
// ---------------------------------------------------------------------------
__global__ __launch_bounds__(256, 4) void flash_attn7(
    const u16* __restrict__ Q, const u16* __restrict__ Kr, const u16* __restrict__ Vt,
    u16* __restrict__ O)
{
    const int qt = blockIdx.x;        // 0..15 (128 q-rows each)
    const int bh = blockIdx.y;        // 0..31
    const int b = bh >> 4, h = bh & 15;
    const int tid = threadIdx.x, l = tid & 63, w = tid >> 6;
    const int quad = l >> 4, lan = l & 15;

    __shared__ __attribute__((aligned(16))) u16 Kb[2][8 * 512];
    __shared__ __attribute__((aligned(16))) u16 VTb[2][8 * 512];
    __shared__ __attribute__((aligned(16))) u16 Pb[4][32 * 40];

    // Q frags for both q-groups (rows w*32 + g*16 + lan); pre-scaled by ATT
    f16x8 qf0[4], qf1[4];
    {
        const u16* qp = Q + ((size_t)(b * 2048 + qt * 128 + w * 32 + lan)) * 2048 + h * 128 + quad * 8;
#pragma unroll
        for (int ks = 0; ks < 4; ks++) {
            qf0[ks] = __builtin_bit_cast(f16x8, *(const u16x8*)(qp + ks * 32));
            qf1[ks] = __builtin_bit_cast(f16x8, *(const u16x8*)(qp + 16 * 2048 + ks * 32));
        }
    }

    // K staging: wave w fills groups {2w, 2w+1}; group gk: row nt*16+(l&15),
    // d-chunk ks*32 + (l>>4)*8 with nt = gk>>2, ks = gk&3.
    const u16* kbase = Kr + ((size_t)(b * 2048)) * 2048 + h * 128;
    const int gk0 = 2 * w, gk1 = 2 * w + 1;
    const int krow0 = (gk0 >> 2) * 16 + lan, kcol0 = (gk0 & 3) * 32 + quad * 8;
    const int krow1 = (gk1 >> 2) * 16 + lan, kcol1 = (gk1 & 3) * 32 + quad * 8;
    // VT staging: wave w fills groups {2w, 2w+1}; group nd: d-row nd*16+(l&15),
    // kv-chunk (l>>4)*8.
    const u16* vbase = Vt + ((size_t)((b * 16 + h) * 128)) * 2048;
    const int vrow0 = gk0 * 16 + lan;
    const int vrow1 = gk1 * 16 + lan;
    const int vcol  = quad * 8;

    float mr0 = -3.0e38f, lrp0 = 0.f;
    float mr1 = -3.0e38f, lrp1 = 0.f;
    f32x4 o0[8] = {}, o1[8] = {};

    // issue DMA for tile 0 into buf 0
    g2l16(kbase + (size_t)krow0 * 2048 + kcol0, &Kb[0][gk0 * 512]);
    g2l16(kbase + (size_t)krow1 * 2048 + kcol1, &Kb[0][gk1 * 512]);
    g2l16(vbase + (size_t)vrow0 * 2048 + vcol, &VTb[0][gk0 * 512]);
    g2l16(vbase + (size_t)vrow1 * 2048 + vcol, &VTb[0][gk1 * 512]);
    __syncthreads();   // drain tile-0 DMA

    for (int kt = 0; kt < 64; kt++) {
        const int buf = kt & 1;
        // prefetch tile kt+1 into other buffer (completes during compute)
        if (kt < 63) {
            const int kn = (kt + 1) * 32;
            g2l16(kbase + (size_t)(kn + krow0) * 2048 + kcol0, &Kb[buf ^ 1][gk0 * 512]);
            g2l16(kbase + (size_t)(kn + krow1) * 2048 + kcol1, &Kb[buf ^ 1][gk1 * 512]);
            g2l16(vbase + (size_t)vrow0 * 2048 + kn + vcol, &VTb[buf ^ 1][gk0 * 512]);
            g2l16(vbase + (size_t)vrow1 * 2048 + kn + vcol, &VTb[buf ^ 1][gk1 * 512]);
        }

        // S^T = K Q^T : kb read once (linear, conflict-free), both q-groups
        f32x4 s0[2] = {}, s1[2] = {};
        __builtin_amdgcn_s_setprio(1);
#pragma unroll
        for (int ks = 0; ks < 4; ks++)
#pragma unroll
            for (int nt = 0; nt < 2; nt++) {
                f16x8 kb = __builtin_bit_cast(f16x8, *(const u16x8*)(
                    &Kb[buf][((nt * 4 + ks) * 64 + l) * 8]));
                s0[nt] = __builtin_amdgcn_mfma_f32_16x16x32_f16(kb, qf0[ks], s0[nt], 0, 0, 0);
                s1[nt] = __builtin_amdgcn_mfma_f32_16x16x32_f16(kb, qf1[ks], s1[nt], 0, 0, 0);
            }
        __builtin_amdgcn_s_setprio(0);

        // per-lane scalar online softmax, per q-group
        float tm0 = fmaxf(fmaxf(fmaxf(s0[0][0], s0[0][1]), fmaxf(s0[0][2], s0[0][3])),
                          fmaxf(fmaxf(s0[1][0], s0[1][1]), fmaxf(s0[1][2], s0[1][3])));
        float tm1 = fmaxf(fmaxf(fmaxf(s1[0][0], s1[0][1]), fmaxf(s1[0][2], s1[0][3])),
                          fmaxf(fmaxf(s1[1][0], s1[1][1]), fmaxf(s1[1][2], s1[1][3])));
        tm0 = fmaxf(tm0, __shfl_xor(tm0, 16)); tm0 = fmaxf(tm0, __shfl_xor(tm0, 32));
        tm1 = fmaxf(tm1, __shfl_xor(tm1, 16)); tm1 = fmaxf(tm1, __shfl_xor(tm1, 32));

        if (!__all(tm0 <= mr0 + 4.0f)) {
            const float nm = fmaxf(mr0, tm0);
            const float al = exp2f((mr0 - nm) * LOG2E);
            mr0 = nm; lrp0 *= al;
#pragma unroll
            for (int nd = 0; nd < 8; nd++)
#pragma unroll
                for (int r = 0; r < 4; r++) o0[nd][r] *= al;
        }
        if (!__all(tm1 <= mr1 + 4.0f)) {
            const float nm = fmaxf(mr1, tm1);
            const float al = exp2f((mr1 - nm) * LOG2E);
            mr1 = nm; lrp1 *= al;
#pragma unroll
            for (int nd = 0; nd < 8; nd++)
#pragma unroll
                for (int r = 0; r < 4; r++) o1[nd][r] *= al;
        }

        float ps0 = 0.f, ps1 = 0.f;
        u16x4 a0, a1, b0, b1;
#pragma unroll
        for (int r = 0; r < 4; r++) {
            float p = exp2f((s0[0][r] - mr0) * LOG2E); ps0 += p; a0[r] = f2h(p);
            p = exp2f((s0[1][r] - mr0) * LOG2E);       ps0 += p; a1[r] = f2h(p);
            p = exp2f((s1[0][r] - mr1) * LOG2E);       ps1 += p; b0[r] = f2h(p);
            p = exp2f((s1[1][r] - mr1) * LOG2E);       ps1 += p; b1[r] = f2h(p);
        }
        lrp0 += ps0; lrp1 += ps1;

        // stage P[q_local][k]: q_local = g*16 + lan, 32 k per row (+8 pad)
        *(u16x4*)(&Pb[w][lan * 40 + quad * 4])             = a0;
        *(u16x4*)(&Pb[w][lan * 40 + 16 + quad * 4])        = a1;
        *(u16x4*)(&Pb[w][(16 + lan) * 40 + quad * 4])      = b0;
        *(u16x4*)(&Pb[w][(16 + lan) * 40 + 16 + quad * 4]) = b1;

        __asm__ volatile("s_waitcnt lgkmcnt(0)" ::: "memory");  // own-wave P visible

        // O^T += V^T P^T : vtf read once (linear, conflict-free), both groups
        f16x8 pf0 = __builtin_bit_cast(f16x8, *(const u16x8*)(&Pb[w][lan * 40 + quad * 8]));
        f16x8 pf1 = __builtin_bit_cast(f16x8, *(const u16x8*)(&Pb[w][(16 + lan) * 40 + quad * 8]));
        __builtin_amdgcn_s_setprio(1);
#pragma unroll
        for (int nd = 0; nd < 8; nd++) {
            f16x8 vtf = __builtin_bit_cast(f16x8, *(const u16x8*)(
                &VTb[buf][(nd * 64 + l) * 8]));
            o0[nd] = __builtin_amdgcn_mfma_f32_16x16x32_f16(vtf, pf0, o0[nd], 0, 0, 0);
            o1[nd] = __builtin_amdgcn_mfma_f32_16x16x32_f16(vtf, pf1, o1[nd], 0, 0, 0);
        }
        __builtin_amdgcn_s_setprio(0);

        __syncthreads();   // drains kt+1 DMA (had full compute to land) + syncs
    }

    // finalize deferred sums across quads (disjoint k-subsets)
    lrp0 += __shfl_xor(lrp0, 16); lrp0 += __shfl_xor(lrp0, 32);
    lrp1 += __shfl_xor(lrp1, 16); lrp1 += __shfl_xor(lrp1, 32);
    const float inv0 = 1.0f / lrp0;
    const float inv1 = 1.0f / lrp1;

    // O^T lane layout: q = lan, d = nd*16 + quad*4 + r
    u16* Or = O + ((size_t)(b * 2048 + qt * 128 + w * 32 + lan)) * 2048 + h * 128 + quad * 4;
#pragma unroll
    for (int nd = 0; nd < 8; nd++) {
        u16x4 ov;
#pragma unroll
        for (int r = 0; r < 4; r++) ov[r] = f2h(o0[nd][r] * inv0);
        *(u16x4*)(Or + nd * 16) = ov;
    }
    Or += (size_t)16 * 2048;
#pragma unroll
    for (int nd = 0; nd < 8; nd++) {
        u16x4 ov;
#pragma unroll
        for (int r = 0; r < 4; r++) ov[r] = f2h(o1[nd][r] * inv1);
        *(u16x4*)(Or + nd * 16) = ov;
    }
}

// ---------------------------------------------------------------------------
// Output projection v3: fragment-major LDS, triple-buffered counted-vmcnt.
// A = aout f16, B = Wo16 f16, C fp32.
// ---------------------------------------------------------------------------
__global__ __launch_bounds__(256, 4) void gemm_out(
    const u16* __restrict__ A, const u16* __restrict__ W,
    const float* __restrict__ bias, float* __restrict__ C)
{
    constexpr int K = 2048, N = 2048, NT = K / 32;
    const int m0 = blockIdx.y * 128, n0 = blockIdx.x * 128;

    __shared__ __attribute__((aligned(16))) u16 As[3][8 * 512];
    __shared__ __attribute__((aligned(16))) u16 Bs[3][8 * 512];

    const int tid = threadIdx.x, l = tid & 63, w = tid >> 6;
    const int quad = l >> 4, lan = l & 15;

    const u16* pA0 = A + (size_t)(m0 + 32 * w + lan) * K + quad * 8;
    const u16* pA1 = A + (size_t)(m0 + 32 * w + 16 + lan) * K + quad * 8;
    const u16* pB0 = W + (size_t)(n0 + 32 * w + lan) * K + quad * 8;
    const u16* pB1 = W + (size_t)(n0 + 32 * w + 16 + lan) * K + quad * 8;
    const int dG0 = (2 * w) * 512;
    const int dG1 = (2 * w + 1) * 512;

    const int wm = (w >> 1) * 64, wn = (w & 1) * 64;
    const int ga0 = (w >> 1) * 4;
    const int gb0 = (w & 1) * 4;

    f32x4 acc[4][4] = {};

    {
        g2l16(pA0, &As[0][dG0]); g2l16(pA1, &As[0][dG1]);
        g2l16(pB0, &Bs[0][dG0]); g2l16(pB1, &Bs[0][dG1]);
        g2l16(pA0 + 32, &As[1][dG0]); g2l16(pA1 + 32, &As[1][dG1]);
        g2l16(pB0 + 32, &Bs[1][dG0]); g2l16(pB1 + 32, &Bs[1][dG1]);
    }
    __asm__ volatile("s_waitcnt vmcnt(4)" ::: "memory");
    __builtin_amdgcn_s_barrier();
    __builtin_amdgcn_sched_barrier(0);

    int bc = 0;
    for (int t = 0; t < NT; ++t) {
        int bi = bc + 2; if (bi >= 3) bi -= 3;
        if (t + 2 < NT) {
            const int kk = (t + 2) * 32;
            g2l16(pA0 + kk, &As[bi][dG0]); g2l16(pA1 + kk, &As[bi][dG1]);
            g2l16(pB0 + kk, &Bs[bi][dG0]); g2l16(pB1 + kk, &Bs[bi][dG1]);
        }

        const u16* Ab = As[bc];
        const u16* Bb = Bs[bc];
        f16x8 af[4], bf[4];
#pragma unroll
        for (int i = 0; i < 4; i++)
            af[i] = __builtin_bit_cast(f16x8, *(const u16x8*)(&Ab[((ga0 + i) * 64 + l) * 8]));
#pragma unroll
        for (int j = 0; j < 4; j++)
            bf[j] = __builtin_bit_cast(f16x8, *(const u16x8*)(&Bb[((gb0 + j) * 64 + l) * 8]));

        __builtin_amdgcn_s_setprio(1);
#pragma unroll
        for (int i = 0; i < 4; i++)
#pragma unroll
            for (int j = 0; j < 4; j++)
                acc[i][j] = __builtin_amdgcn_mfma_f32_16x16x32_f16(af[i], bf[j], acc[i][j], 0, 0, 0);
        __builtin_amdgcn_s_setprio(0);

        if (t + 1 < NT) {
            if (t + 2 < NT) { __asm__ volatile("s_waitcnt vmcnt(4)" ::: "memory"); }
            else            { __asm__ volatile("s_waitcnt vmcnt(0)" ::: "memory"); }
            __builtin_amdgcn_s_barrier();
            __builtin_amdgcn_sched_barrier(0);
        }
        bc = (bc == 2) ? 0 : bc + 1;
    }

#pragma unroll
    for (int j = 0; j < 4; j++) {
        const int col = n0 + wn + j * 16 + lan;
        const float bj = bias[col];
#pragma unroll
        for (int i = 0; i < 4; i++)
#pragma unroll
            for (int r = 0; r < 4; r++) {
                const int row = m0 + wm + i * 16 + quad * 4 + r;
                C[(size_t)row * N + col] = acc[i][j][r] + bj;
            }
    }
}

// ---------------------------------------------------------------------------
extern "C" void kernel_launch(void* const* d_in, const int* in_sizes, int n_in,
                              void* d_out, int out_size, void* d_ws, size_t ws_size,
                              hipStream_t stream) {
    const float* hs  = (const float*)d_in[0];
    const float* rot = (const float*)d_in[1];
    const float* Wq  = (const float*)d_in[2];
    const float* bq  = (const float*)d_in[3];
    const float* Wk  = (const float*)d_in[4];
    const float* bk  = (const float*)d_in[5];
    const float* Wv  = (const float*)d_in[6];
    const float* bv  = (const float*)d_in[7];
    const float* nqw = (const float*)d_in[8];
    const float* nkw = (const float*)d_in[9];
    const float* hks = (const float*)d_in[10];
    const float* Wo  = (const float*)d_in[11];
    const float* bo  = (const float*)d_in[12];
    const int*   ocl = (const int*)d_in[13];

    // ws (64 MiB): [0:16) qraw | [16:32) kraw | [32:48) vtr | [48:64) aout
    // aout region holds Wq16/Wk16 until flash overwrites it (they're dead then).
    u16* qraw = (u16*)d_ws;
    u16* kraw = qraw + 8388608;
    u16* vtr  = kraw + 8388608;
    u16* aout = vtr + 8388608;
    u16* wq16 = aout;                  // [48:56 MiB)
    u16* wk16 = aout + 4194304;        // [56:64 MiB)
    u16* wo16 = qraw;                  // reuses qraw AFTER flash
    float* out = (float*)d_out;
    u16* hs16 = (u16*)d_out;           // d_out [0:16 MiB)
    u16* wv16 = hs16 + 8388608;        // d_out [16:24 MiB)

    // 0) convert hs + Wq/Wk/Wv to f16
    cvt4<<<dim3(10240), 256, 0, stream>>>(hs, Wq, Wk, Wv, hs16, wq16, wk16, wv16);
    // 1) QKV projection (fragment-major LDS, counted-vmcnt); z=2 writes V^T
    gemm_qkv<<<dim3(16, 32, 3), 256, 0, stream>>>(
        hs16, wq16, wk16, wv16, bq, bk, bv, qraw, kraw, vtr);
    // 2) rmsnorm + rope + history scale
    norm_rope<<<dim3(4096), 256, 0, stream>>>(qraw, kraw, rot, nqw, nkw, hks, ocl);
    // 3) flash attention v7 (fragment-major K/VT) -> aout
    flash_attn7<<<dim3(16, 32), 256, 0, stream>>>(qraw, kraw, vtr, aout);
    // 4) Wo -> f16 into dead qraw region, then output projection -> d_out
    cvt1<<<dim3(2048), 256, 0, stream>>>(Wo, wo16);
    gemm_out<<<dim3(16, 32), 256, 0, stream>>>(aout, wo16, bo, out);
}

// Round 5
// 484.247 us; speedup vs baseline: 1.1759x; 1.1759x over previous
//
#include <hip/hip_runtime.h>
#include <math.h>

typedef unsigned short u16;
typedef unsigned short u16x8 __attribute__((ext_vector_type(8)));
typedef unsigned short u16x4 __attribute__((ext_vector_type(4)));
typedef _Float16 f16x8 __attribute__((ext_vector_type(8)));
typedef float f32x4 __attribute__((ext_vector_type(4)));

#define LOG2E 1.4426950408889634f

static __device__ __forceinline__ u16 f2h(float f) { return __builtin_bit_cast(u16, (_Float16)f); }
static __device__ __forceinline__ float h2f(u16 u) { return (float)__builtin_bit_cast(_Float16, u); }

// async global->LDS, 16B per lane; LDS dest = wave-uniform base + lane*16
static __device__ __forceinline__ void g2l16(const u16* g, u16* l) {
    __builtin_amdgcn_global_load_lds(
        (const __attribute__((address_space(1))) void*)g,
        (__attribute__((address_space(3))) void*)l, 16, 0, 0);
}

static __device__ __forceinline__ u16x8 ld8f(const float* p) {
    f32x4 a = *(const f32x4*)p;
    f32x4 b = *(const f32x4*)(p + 4);
    u16x8 r;
    r[0] = f2h(a[0]); r[1] = f2h(a[1]); r[2] = f2h(a[2]); r[3] = f2h(a[3]);
    r[4] = f2h(b[0]); r[5] = f2h(b[1]); r[6] = f2h(b[2]); r[7] = f2h(b[3]);
    return r;
}

// ---------------------------------------------------------------------------
// Tiled "DMA-order" layout for GEMM operands: matrix [M][2048] stored as
// 16x32 tiles, tile T = (row/16)*64 + (col/32), 1KB contiguous; within tile
// slot s = ((col>>3)&3)*16 + (row&15) holds 8 consecutive elements.
// A g2l16 of one tile is a fully contiguous 1KB read, and the LDS image is
// fragment-major: lane l's MFMA fragment = slot l (conflict-free reads).
// ---------------------------------------------------------------------------

// fused fp32->f16 convert INTO tiled layout.
// block = (R, slab): 16 rows x 128 cols; thread t: row R*16+(t>>4),
// col slab*128 + (t&15)*8 -> tile C = slab*4 + ((t>>2)&3), slot (t&3)*16+(t>>4).
__global__ __launch_bounds__(256) void cvt4(
    const float* __restrict__ hs, const float* __restrict__ Wq,
    const float* __restrict__ Wk, const float* __restrict__ Wv,
    u16* __restrict__ hs16, u16* __restrict__ wq16,
    u16* __restrict__ wk16, u16* __restrict__ wv16)
{
    int blk = blockIdx.x;
    const float* s; u16* d;
    if (blk < 4096)      { s = hs; d = hs16; }
    else if (blk < 6144) { s = Wq; d = wq16; blk -= 4096; }
    else if (blk < 8192) { s = Wk; d = wk16; blk -= 6144; }
    else                 { s = Wv; d = wv16; blk -= 8192; }
    const int R = blk >> 4, slab = blk & 15;
    const int t = threadIdx.x;
    const int row = R * 16 + (t >> 4);
    const int col = slab * 128 + (t & 15) * 8;
    u16x8 v = ld8f(s + (size_t)row * 2048 + col);
    const size_t o = ((size_t)(R * 64 + slab * 4 + ((t >> 2) & 3))) * 512
                   + ((t & 3) * 16 + (t >> 4)) * 8;
    *(u16x8*)(d + o) = v;
}

__global__ __launch_bounds__(256) void cvt1(const float* __restrict__ s, u16* __restrict__ d) {
    const int blk = blockIdx.x;
    const int R = blk >> 4, slab = blk & 15;
    const int t = threadIdx.x;
    const int row = R * 16 + (t >> 4);
    const int col = slab * 128 + (t & 15) * 8;
    u16x8 v = ld8f(s + (size_t)row * 2048 + col);
    const size_t o = ((size_t)(R * 64 + slab * 4 + ((t >> 2) & 3))) * 512
                   + ((t & 3) * 16 + (t >> 4)) * 8;
    *(u16x8*)(d + o) = v;
}

// ---------------------------------------------------------------------------
// QKV GEMM v4: tiled-input DMA (1KB contiguous per issue) + fragment-major
// LDS (0 conflicts) + triple-buffered counted-vmcnt schedule.
// z=0->Q, 1->K ([b*s][h*d] row-major); z=2->V^T [b,h,d,s] row-major.
// ---------------------------------------------------------------------------
__global__ __launch_bounds__(256, 4) void gemm_qkv(
    const u16* __restrict__ A,
    const u16* __restrict__ W0, const u16* __restrict__ W1, const u16* __restrict__ W2,
    const float* __restrict__ B0, const float* __restrict__ B1, const float* __restrict__ B2,
    u16* __restrict__ Cq, u16* __restrict__ Ck, u16* __restrict__ Cvt)
{
    constexpr int N = 2048, NT = 64;
    const int z = blockIdx.z;
    const u16* W      = (z == 0) ? W0 : ((z == 1) ? W1 : W2);
    const float* bias = (z == 0) ? B0 : ((z == 1) ? B1 : B2);
    const int m0 = blockIdx.y * 128, n0 = blockIdx.x * 128;

    __shared__ __attribute__((aligned(16))) u16 As[3][8 * 512];
    __shared__ __attribute__((aligned(16))) u16 Bs[3][8 * 512];

    const int tid = threadIdx.x, l = tid & 63, w = tid >> 6;
    const int quad = l >> 4, lan = l & 15;

    // tiled sources: group g (= 16-row slice g of the 128-row block) at
    // k-step t lives at tile ((m0/16+g)*64 + t) * 512; lane offset l*8.
    const u16* pA0 = A + ((size_t)((m0 >> 4) + 2 * w) * 64) * 512 + l * 8;
    const u16* pA1 = A + ((size_t)((m0 >> 4) + 2 * w + 1) * 64) * 512 + l * 8;
    const u16* pB0 = W + ((size_t)((n0 >> 4) + 2 * w) * 64) * 512 + l * 8;
    const u16* pB1 = W + ((size_t)((n0 >> 4) + 2 * w + 1) * 64) * 512 + l * 8;
    const int dG0 = (2 * w) * 512;
    const int dG1 = (2 * w + 1) * 512;

    const int wm = (w >> 1) * 64, wn = (w & 1) * 64;
    const int ga0 = (w >> 1) * 4;    // A-groups ga0..ga0+3
    const int gb0 = (w & 1) * 4;     // B-groups gb0..gb0+3

    f32x4 acc[4][4] = {};

    // prologue: tiles 0 and 1 in flight; wait tile 0 (leave tile 1's 4 loads)
    {
        g2l16(pA0, &As[0][dG0]); g2l16(pA1, &As[0][dG1]);
        g2l16(pB0, &Bs[0][dG0]); g2l16(pB1, &Bs[0][dG1]);
        g2l16(pA0 + 512, &As[1][dG0]); g2l16(pA1 + 512, &As[1][dG1]);
        g2l16(pB0 + 512, &Bs[1][dG0]); g2l16(pB1 + 512, &Bs[1][dG1]);
    }
    __asm__ volatile("s_waitcnt vmcnt(4)" ::: "memory");
    __builtin_amdgcn_s_barrier();
    __builtin_amdgcn_sched_barrier(0);

    int bc = 0;
    for (int t = 0; t < NT; ++t) {
        int bi = bc + 2; if (bi >= 3) bi -= 3;
        if (t + 2 < NT) {
            const int kk = (t + 2) * 512;
            g2l16(pA0 + kk, &As[bi][dG0]); g2l16(pA1 + kk, &As[bi][dG1]);
            g2l16(pB0 + kk, &Bs[bi][dG0]); g2l16(pB1 + kk, &Bs[bi][dG1]);
        }

        const u16* Ab = As[bc];
        const u16* Bb = Bs[bc];
        f16x8 af[4], bf[4];
#pragma unroll
        for (int i = 0; i < 4; i++)
            af[i] = __builtin_bit_cast(f16x8, *(const u16x8*)(&Ab[((ga0 + i) * 64 + l) * 8]));
#pragma unroll
        for (int j = 0; j < 4; j++)
            bf[j] = __builtin_bit_cast(f16x8, *(const u16x8*)(&Bb[((gb0 + j) * 64 + l) * 8]));

        __builtin_amdgcn_s_setprio(1);
#pragma unroll
        for (int i = 0; i < 4; i++)
#pragma unroll
            for (int j = 0; j < 4; j++)
                acc[i][j] = __builtin_amdgcn_mfma_f32_16x16x32_f16(af[i], bf[j], acc[i][j], 0, 0, 0);
        __builtin_amdgcn_s_setprio(0);

        if (t + 1 < NT) {
            if (t + 2 < NT) { __asm__ volatile("s_waitcnt vmcnt(4)" ::: "memory"); }
            else            { __asm__ volatile("s_waitcnt vmcnt(0)" ::: "memory"); }
            __builtin_amdgcn_s_barrier();
            __builtin_amdgcn_sched_barrier(0);
        }
        bc = (bc == 2) ? 0 : bc + 1;
    }

    if (z < 2) {
        u16* C = (z == 0) ? Cq : Ck;
#pragma unroll
        for (int j = 0; j < 4; j++) {
            const int col = n0 + wn + j * 16 + lan;
            const float bj = bias[col];
#pragma unroll
            for (int i = 0; i < 4; i++)
#pragma unroll
                for (int r = 0; r < 4; r++) {
                    const int row = m0 + wm + i * 16 + quad * 4 + r;
                    C[(size_t)row * N + col] = f2h(acc[i][j][r] + bj);
                }
        }
    } else {
        // V transposed: row=(b,s), col=(h,d) -> Cvt[((b*16+h)*128+d)*2048 + s]
#pragma unroll
        for (int j = 0; j < 4; j++) {
            const int col = n0 + wn + j * 16 + lan;
            const int hh = col >> 7, dd = col & 127;
            const float bj = bias[col];
            u16* Cr = Cvt + ((size_t)hh * 128 + dd) * 2048;
#pragma unroll
            for (int i = 0; i < 4; i++) {
                const int row0 = m0 + wm + i * 16 + quad * 4;
                const int bb = row0 >> 11, ss = row0 & 2047;
                u16x4 pv;
#pragma unroll
                for (int r = 0; r < 4; r++) pv[r] = f2h(acc[i][j][r] + bj);
                *(u16x4*)(Cr + (size_t)bb * 4194304 + ss) = pv;
            }
        }
    }
}

// ---------------------------------------------------------------------------
// RMSNorm + RoPE + history key scale; in-place f16 q/k; q *= 1/sqrt(128).
// ---------------------------------------------------------------------------
__global__ __launch_bounds__(256) void norm_rope(
    u16* __restrict__ q, u16* __restrict__ k,
    const float* __restrict__ rot,
    const float* __restrict__ nqw, const float* __restrict__ nkw,
    const float* __restrict__ hks, const int* __restrict__ oclp)
{
    const int row = blockIdx.x;
    const int s = row & 2047;
    const int t = threadIdx.x;
    const size_t base = (size_t)row * 2048 + t * 8;

    u16x8 q8 = *(const u16x8*)(q + base);
    u16x8 k8 = *(const u16x8*)(k + base);

    float qf[8], kf[8];
    float sq = 0.f, sk = 0.f;
#pragma unroll
    for (int i = 0; i < 8; i++) {
        qf[i] = h2f(q8[i]); sq += qf[i] * qf[i];
        kf[i] = h2f(k8[i]); sk += kf[i] * kf[i];
    }
#pragma unroll
    for (int off = 32; off > 0; off >>= 1) {
        sq += __shfl_down(sq, off);
        sk += __shfl_down(sk, off);
    }
    __shared__ float rq[4], rk[4];
    const int wv = t >> 6;
    if ((t & 63) == 0) { rq[wv] = sq; rk[wv] = sk; }
    __syncthreads();
    const float tq = rq[0] + rq[1] + rq[2] + rq[3];
    const float tk = rk[0] + rk[1] + rk[2] + rk[3];
    const float scq = rsqrtf(tq * (1.0f / 2048.0f) + 1e-5f);
    const float sck = rsqrtf(tk * (1.0f / 2048.0f) + 1e-5f);
#pragma unroll
    for (int i = 0; i < 8; i++) {
        qf[i] *= scq * nqw[t * 8 + i];
        kf[i] *= sck * nkw[t * 8 + i];
    }
    const int e0 = t * 8;
    const int dh0 = e0 & 127;
    const int h = e0 >> 7;
    float qo[8], ko[8];
#pragma unroll
    for (int p = 0; p < 4; p++) {
        const int dh = dh0 + 2 * p;
        const float c  = rot[s * 256 + dh];
        const float sn = rot[s * 256 + 128 + dh + 1];
        qo[2 * p]     = qf[2 * p] * c  - qf[2 * p + 1] * sn;
        qo[2 * p + 1] = qf[2 * p] * sn + qf[2 * p + 1] * c;
        ko[2 * p]     = kf[2 * p] * c  - kf[2 * p + 1] * sn;
        ko[2 * p + 1] = kf[2 * p] * sn + kf[2 * p + 1] * c;
    }
    const float ATT = 0.08838834764831845f;
#pragma unroll
    for (int i = 0; i < 8; i++) qo[i] *= ATT;

    const int hist = 2048 - oclp[0];
    if (s < hist) {
        const float hv = hks[h];
        const float scl = 1.0f + 9.0f / (1.0f + expf(-hv));
#pragma unroll
        for (int i = 0; i < 8; i++) ko[i] *= scl;
    }

    u16x8 qo8, ko8;
#pragma unroll
    for (int i = 0; i < 8; i++) { qo8[i] = f2h(qo[i]); ko8[i] = f2h(ko[i]); }
    *(u16x8*)(q + base) = qo8;
    *(u16x8*)(k + base) = ko8;
}

// ---------------------------------------------------------------------------
// Flash attention v8 = verified v6 (R3) with TILED aout epilogue.
// 32 q-rows/wave (2 q-groups), QBLK=128/block, grid 16x32; K/V^T XOR-staged
// row-major double-buffered LDS; swapped-operand MFMAs; scalar softmax.
// ---------------------------------------------------------------------------
__global__ __launch_bounds__(256, 4) void flash_attn8(
    const u16* __restrict__ Q, const u16* __restrict__ Kr, const u16* __restrict__ Vt,
    u16* __restrict__ O)
{
    const int qt = blockIdx.x;        // 0..15 (128 q-rows each)
    const int bh = blockIdx.y;        // 0..31
    const int b = bh >> 4, h = bh & 15;
    const int tid = threadIdx.x, l = tid & 63, w = tid >> 6;
    const int quad = l >> 4, lan = l & 15;

    __shared__ __attribute__((aligned(16))) u16 Kb[2][32 * 128];
    __shared__ __attribute__((aligned(16))) u16 VTb[2][128 * 32];
    __shared__ __attribute__((aligned(16))) u16 Pb[4][32 * 40];

    // Q frags for both q-groups (rows w*32 + g*16 + lan); pre-scaled by ATT
    f16x8 qf0[4], qf1[4];
    {
        const u16* qp = Q + ((size_t)(b * 2048 + qt * 128 + w * 32 + lan)) * 2048 + h * 128 + quad * 8;
#pragma unroll
        for (int ks = 0; ks < 4; ks++) {
            qf0[ks] = __builtin_bit_cast(f16x8, *(const u16x8*)(qp + ks * 32));
            qf1[ks] = __builtin_bit_cast(f16x8, *(const u16x8*)(qp + 16 * 2048 + ks * 32));
        }
    }

    // K staging: 2 issues; issue i: row = w*4 + 16i + (l>>4), chunk l&15,
    // source chunk XOR'd by row&15. LDS layout [32][128] row-major.
    const int krow_b = w * 4 + (l >> 4);
    const int kchk   = l & 15;
    const u16* kbase = Kr + ((size_t)(b * 2048)) * 2048 + h * 128;
    // VT staging: 2 issues; row = w*16 + 64i + (l>>2), chunk l&3,
    // source chunk XOR'd by (l>>3)&3. LDS [128][32].
    const int vrow_b = w * 16 + (l >> 2);
    const int vg     = ((l & 3) ^ ((l >> 3) & 3)) * 8;
    const u16* vbase = Vt + ((size_t)((b * 16 + h) * 128)) * 2048;

    float mr0 = -3.0e38f, lrp0 = 0.f;
    float mr1 = -3.0e38f, lrp1 = 0.f;
    f32x4 o0[8] = {}, o1[8] = {};

    // issue DMA for tile 0 into buf 0
#pragma unroll
    for (int i = 0; i < 2; i++) {
        const int kr = krow_b + 16 * i;
        g2l16(kbase + (size_t)kr * 2048 + ((kchk ^ (kr & 15)) * 8), &Kb[0][(w * 64 + 256 * i) * 8]);
    }
#pragma unroll
    for (int i = 0; i < 2; i++) {
        const int vr = vrow_b + 64 * i;
        g2l16(vbase + (size_t)vr * 2048 + vg, &VTb[0][(w * 64 + 256 * i) * 8]);
    }
    __syncthreads();   // drain tile-0 DMA

    for (int kt = 0; kt < 64; kt++) {
        const int buf = kt & 1;
        // prefetch tile kt+1 into other buffer (completes during compute)
        if (kt < 63) {
            const int kn = (kt + 1) * 32;
#pragma unroll
            for (int i = 0; i < 2; i++) {
                const int kr = krow_b + 16 * i;
                g2l16(kbase + (size_t)(kn + kr) * 2048 + ((kchk ^ (kr & 15)) * 8),
                      &Kb[buf ^ 1][(w * 64 + 256 * i) * 8]);
            }
#pragma unroll
            for (int i = 0; i < 2; i++) {
                const int vr = vrow_b + 64 * i;
                g2l16(vbase + (size_t)vr * 2048 + kn + vg,
                      &VTb[buf ^ 1][(w * 64 + 256 * i) * 8]);
            }
        }

        // S^T = K Q^T : kb read once, used for BOTH q-groups
        f32x4 s0[2] = {}, s1[2] = {};
        __builtin_amdgcn_s_setprio(1);
#pragma unroll
        for (int ks = 0; ks < 4; ks++)
#pragma unroll
            for (int nt = 0; nt < 2; nt++) {
                f16x8 kb = __builtin_bit_cast(f16x8, *(const u16x8*)(
                    &Kb[buf][(nt * 16 + lan) * 128 + (((ks * 4 + quad) ^ lan) * 8)]));
                s0[nt] = __builtin_amdgcn_mfma_f32_16x16x32_f16(kb, qf0[ks], s0[nt], 0, 0, 0);
                s1[nt] = __builtin_amdgcn_mfma_f32_16x16x32_f16(kb, qf1[ks], s1[nt], 0, 0, 0);
            }
        __builtin_amdgcn_s_setprio(0);

        // per-lane scalar online softmax, per q-group
        float tm0 = fmaxf(fmaxf(fmaxf(s0[0][0], s0[0][1]), fmaxf(s0[0][2], s0[0][3])),
                          fmaxf(fmaxf(s0[1][0], s0[1][1]), fmaxf(s0[1][2], s0[1][3])));
        float tm1 = fmaxf(fmaxf(fmaxf(s1[0][0], s1[0][1]), fmaxf(s1[0][2], s1[0][3])),
                          fmaxf(fmaxf(s1[1][0], s1[1][1]), fmaxf(s1[1][2], s1[1][3])));
        tm0 = fmaxf(tm0, __shfl_xor(tm0, 16)); tm0 = fmaxf(tm0, __shfl_xor(tm0, 32));
        tm1 = fmaxf(tm1, __shfl_xor(tm1, 16)); tm1 = fmaxf(tm1, __shfl_xor(tm1, 32));

        if (!__all(tm0 <= mr0 + 4.0f)) {
            const float nm = fmaxf(mr0, tm0);
            const float al = exp2f((mr0 - nm) * LOG2E);
            mr0 = nm; lrp0 *= al;
#pragma unroll
            for (int nd = 0; nd < 8; nd++)
#pragma unroll
                for (int r = 0; r < 4; r++) o0[nd][r] *= al;
        }
        if (!__all(tm1 <= mr1 + 4.0f)) {
            const float nm = fmaxf(mr1, tm1);
            const float al = exp2f((mr1 - nm) * LOG2E);
            mr1 = nm; lrp1 *= al;
#pragma unroll
            for (int nd = 0; nd < 8; nd++)
#pragma unroll
                for (int r = 0; r < 4; r++) o1[nd][r] *= al;
        }

        float ps0 = 0.f, ps1 = 0.f;
        u16x4 a0, a1, b0, b1;
#pragma unroll
        for (int r = 0; r < 4; r++) {
            float p = exp2f((s0[0][r] - mr0) * LOG2E); ps0 += p; a0[r] = f2h(p);
            p = exp2f((s0[1][r] - mr0) * LOG2E);       ps0 += p; a1[r] = f2h(p);
            p = exp2f((s1[0][r] - mr1) * LOG2E);       ps1 += p; b0[r] = f2h(p);
            p = exp2f((s1[1][r] - mr1) * LOG2E);       ps1 += p; b1[r] = f2h(p);
        }
        lrp0 += ps0; lrp1 += ps1;

        // stage P[q_local][k]: q_local = g*16 + lan, 32 k per row (+8 pad)
        *(u16x4*)(&Pb[w][lan * 40 + quad * 4])             = a0;
        *(u16x4*)(&Pb[w][lan * 40 + 16 + quad * 4])        = a1;
        *(u16x4*)(&Pb[w][(16 + lan) * 40 + quad * 4])      = b0;
        *(u16x4*)(&Pb[w][(16 + lan) * 40 + 16 + quad * 4]) = b1;

        __asm__ volatile("s_waitcnt lgkmcnt(0)" ::: "memory");  // own-wave P visible

        // O^T += V^T P^T : vtf read once, used for BOTH q-groups
        f16x8 pf0 = __builtin_bit_cast(f16x8, *(const u16x8*)(&Pb[w][lan * 40 + quad * 8]));
        f16x8 pf1 = __builtin_bit_cast(f16x8, *(const u16x8*)(&Pb[w][(16 + lan) * 40 + quad * 8]));
        __builtin_amdgcn_s_setprio(1);
#pragma unroll
        for (int nd = 0; nd < 8; nd++) {
            f16x8 vtf = __builtin_bit_cast(f16x8, *(const u16x8*)(
                &VTb[buf][(nd * 16 + lan) * 32 + ((quad ^ ((lan >> 1) & 3)) * 8)]));
            o0[nd] = __builtin_amdgcn_mfma_f32_16x16x32_f16(vtf, pf0, o0[nd], 0, 0, 0);
            o1[nd] = __builtin_amdgcn_mfma_f32_16x16x32_f16(vtf, pf1, o1[nd], 0, 0, 0);
        }
        __builtin_amdgcn_s_setprio(0);

        __syncthreads();   // drains kt+1 DMA (had full compute to land) + syncs
    }

    // finalize deferred sums across quads (disjoint k-subsets)
    lrp0 += __shfl_xor(lrp0, 16); lrp0 += __shfl_xor(lrp0, 32);
    lrp1 += __shfl_xor(lrp1, 16); lrp1 += __shfl_xor(lrp1, 32);
    const float inv0 = 1.0f / lrp0;
    const float inv1 = 1.0f / lrp1;

    // TILED aout epilogue: m = b*2048 + qt*128 + w*32 + g*16 + lan,
    // col = h*128 + nd*16 + quad*4 + r.
    // T = (m>>4)*64 + h*4 + (nd>>1); slot = ((nd&1)*2 + (quad>>1))*16 + lan;
    // elem j0 = (quad&1)*4.
    const int Rb = b * 128 + qt * 8 + w * 2;
#pragma unroll
    for (int nd = 0; nd < 8; nd++) {
        u16x4 ov;
#pragma unroll
        for (int r = 0; r < 4; r++) ov[r] = f2h(o0[nd][r] * inv0);
        const size_t off = ((size_t)(Rb * 64 + h * 4 + (nd >> 1))) * 512
                         + (((nd & 1) * 2 + (quad >> 1)) * 16 + lan) * 8 + (quad & 1) * 4;
        *(u16x4*)(O + off) = ov;
    }
#pragma unroll
    for (int nd = 0; nd < 8; nd++) {
        u16x4 ov;
#pragma unroll
        for (int r = 0; r < 4; r++) ov[r] = f2h(o1[nd][r] * inv1);
        const size_t off = ((size_t)((Rb + 1) * 64 + h * 4 + (nd >> 1))) * 512
                         + (((nd & 1) * 2 + (quad >> 1)) * 16 + lan) * 8 + (quad & 1) * 4;
        *(u16x4*)(O + off) = ov;
    }
}

// ---------------------------------------------------------------------------
// Output projection v4: tiled-input DMA + fragment-major LDS + counted-vmcnt.
// A = aout (tiled) f16, B = Wo16 (tiled) f16, C fp32 row-major.
// ---------------------------------------------------------------------------
__global__ __launch_bounds__(256, 4) void gemm_out(
    const u16* __restrict__ A, const u16* __restrict__ W,
    const float* __restrict__ bias, float* __restrict__ C)
{
    constexpr int N = 2048, NT = 64;
    const int m0 = blockIdx.y * 128, n0 = blockIdx.x * 128;

    __shared__ __attribute__((aligned(16))) u16 As[3][8 * 512];
    __shared__ __attribute__((aligned(16))) u16 Bs[3][8 * 512];

    const int tid = threadIdx.x, l = tid & 63, w = tid >> 6;
    const int quad = l >> 4, lan = l & 15;

    const u16* pA0 = A + ((size_t)((m0 >> 4) + 2 * w) * 64) * 512 + l * 8;
    const u16* pA1 = A + ((size_t)((m0 >> 4) + 2 * w + 1) * 64) * 512 + l * 8;
    const u16* pB0 = W + ((size_t)((n0 >> 4) + 2 * w) * 64) * 512 + l * 8;
    const u16* pB1 = W + ((size_t)((n0 >> 4) + 2 * w + 1) * 64) * 512 + l * 8;
    const int dG0 = (2 * w) * 512;
    const int dG1 = (2 * w + 1) * 512;

    const int wm = (w >> 1) * 64, wn = (w & 1) * 64;
    const int ga0 = (w >> 1) * 4;
    const int gb0 = (w & 1) * 4;

    f32x4 acc[4][4] = {};

    {
        g2l16(pA0, &As[0][dG0]); g2l16(pA1, &As[0][dG1]);
        g2l16(pB0, &Bs[0][dG0]); g2l16(pB1, &Bs[0][dG1]);
        g2l16(pA0 + 512, &As[1][dG0]); g2l16(pA1 + 512, &As[1][dG1]);
        g2l16(pB0 + 512, &Bs[1][dG0]); g2l16(pB1 + 512, &Bs[1][dG1]);
    }
    __asm__ volatile("s_waitcnt vmcnt(4)" ::: "memory");
    __builtin_amdgcn_s_barrier();
    __builtin_amdgcn_sched_barrier(0);

    int bc = 0;
    for (int t = 0; t < NT; ++t) {
        int bi = bc + 2; if (bi >= 3) bi -= 3;
        if (t + 2 < NT) {
            const int kk = (t + 2) * 512;
            g2l16(pA0 + kk, &As[bi][dG0]); g2l16(pA1 + kk, &As[bi][dG1]);
            g2l16(pB0 + kk, &Bs[bi][dG0]); g2l16(pB1 + kk, &Bs[bi][dG1]);
        }

        const u16* Ab = As[bc];
        const u16* Bb = Bs[bc];
        f16x8 af[4], bf[4];
#pragma unroll
        for (int i = 0; i < 4; i++)
            af[i] = __builtin_bit_cast(f16x8, *(const u16x8*)(&Ab[((ga0 + i) * 64 + l) * 8]));
#pragma unroll
        for (int j = 0; j < 4; j++)
            bf[j] = __builtin_bit_cast(f16x8, *(const u16x8*)(&Bb[((gb0 + j) * 64 + l) * 8]));

        __builtin_amdgcn_s_setprio(1);
#pragma unroll
        for (int i = 0; i < 4; i++)
#pragma unroll
            for (int j = 0; j < 4; j++)
                acc[i][j] = __builtin_amdgcn_mfma_f32_16x16x32_f16(af[i], bf[j], acc[i][j], 0, 0, 0);
        __builtin_amdgcn_s_setprio(0);

        if (t + 1 < NT) {
            if (t + 2 < NT) { __asm__ volatile("s_waitcnt vmcnt(4)" ::: "memory"); }
            else            { __asm__ volatile("s_waitcnt vmcnt(0)" ::: "memory"); }
            __builtin_amdgcn_s_barrier();
            __builtin_amdgcn_sched_barrier(0);
        }
        bc = (bc == 2) ? 0 : bc + 1;
    }

#pragma unroll
    for (int j = 0; j < 4; j++) {
        const int col = n0 + wn + j * 16 + lan;
        const float bj = bias[col];
#pragma unroll
        for (int i = 0; i < 4; i++)
#pragma unroll
            for (int r = 0; r < 4; r++) {
                const int row = m0 + wm + i * 16 + quad * 4 + r;
                C[(size_t)row * N + col] = acc[i][j][r] + bj;
            }
    }
}

// ---------------------------------------------------------------------------
extern "C" void kernel_launch(void* const* d_in, const int* in_sizes, int n_in,
                              void* d_out, int out_size, void* d_ws, size_t ws_size,
                              hipStream_t stream) {
    const float* hs  = (const float*)d_in[0];
    const float* rot = (const float*)d_in[1];
    const float* Wq  = (const float*)d_in[2];
    const float* bq  = (const float*)d_in[3];
    const float* Wk  = (const float*)d_in[4];
    const float* bk  = (const float*)d_in[5];
    const float* Wv  = (const float*)d_in[6];
    const float* bv  = (const float*)d_in[7];
    const float* nqw = (const float*)d_in[8];
    const float* nkw = (const float*)d_in[9];
    const float* hks = (const float*)d_in[10];
    const float* Wo  = (const float*)d_in[11];
    const float* bo  = (const float*)d_in[12];
    const int*   ocl = (const int*)d_in[13];

    // ws (64 MiB): [0:16) qraw | [16:32) kraw | [32:48) vtr | [48:64) aout
    // aout region holds Wq16/Wk16 until flash overwrites it (they're dead then).
    u16* qraw = (u16*)d_ws;
    u16* kraw = qraw + 8388608;
    u16* vtr  = kraw + 8388608;
    u16* aout = vtr + 8388608;
    u16* wq16 = aout;                  // [48:56 MiB)
    u16* wk16 = aout + 4194304;        // [56:64 MiB)
    u16* wo16 = qraw;                  // reuses qraw AFTER flash
    float* out = (float*)d_out;
    u16* hs16 = (u16*)d_out;           // d_out [0:16 MiB)
    u16* wv16 = hs16 + 8388608;        // d_out [16:24 MiB)

    // 0) convert hs + Wq/Wk/Wv to f16 (TILED layout)
    cvt4<<<dim3(10240), 256, 0, stream>>>(hs, Wq, Wk, Wv, hs16, wq16, wk16, wv16);
    // 1) QKV projection (tiled DMA + fragment-major LDS); z=2 writes V^T
    gemm_qkv<<<dim3(16, 32, 3), 256, 0, stream>>>(
        hs16, wq16, wk16, wv16, bq, bk, bv, qraw, kraw, vtr);
    // 2) rmsnorm + rope + history scale
    norm_rope<<<dim3(4096), 256, 0, stream>>>(qraw, kraw, rot, nqw, nkw, hks, ocl);
    // 3) flash attention v8 (v6 core, tiled aout epilogue) -> aout
    flash_attn8<<<dim3(16, 32), 256, 0, stream>>>(qraw, kraw, vtr, aout);
    // 4) Wo -> f16 (tiled) into dead qraw region, then output projection
    cvt1<<<dim3(2048), 256, 0, stream>>>(Wo, wo16);
    gemm_out<<<dim3(16, 32), 256, 0, stream>>>(aout, wo16, bo, out);
}

// Round 6
// 470.407 us; speedup vs baseline: 1.2105x; 1.0294x over previous
//
#include <hip/hip_runtime.h>
#include <math.h>

typedef unsigned short u16;
typedef unsigned short u16x8 __attribute__((ext_vector_type(8)));
typedef unsigned short u16x4 __attribute__((ext_vector_type(4)));
typedef _Float16 f16x8 __attribute__((ext_vector_type(8)));
typedef float f32x4 __attribute__((ext_vector_type(4)));

#define LOG2E 1.4426950408889634f

static __device__ __forceinline__ u16 f2h(float f) { return __builtin_bit_cast(u16, (_Float16)f); }
static __device__ __forceinline__ float h2f(u16 u) { return (float)__builtin_bit_cast(_Float16, u); }

// async global->LDS, 16B per lane; LDS dest = wave-uniform base + lane*16
static __device__ __forceinline__ void g2l16(const u16* g, u16* l) {
    __builtin_amdgcn_global_load_lds(
        (const __attribute__((address_space(1))) void*)g,
        (__attribute__((address_space(3))) void*)l, 16, 0, 0);
}

static __device__ __forceinline__ u16x8 ld8f(const float* p) {
    f32x4 a = *(const f32x4*)p;
    f32x4 b = *(const f32x4*)(p + 4);
    u16x8 r;
    r[0] = f2h(a[0]); r[1] = f2h(a[1]); r[2] = f2h(a[2]); r[3] = f2h(a[3]);
    r[4] = f2h(b[0]); r[5] = f2h(b[1]); r[6] = f2h(b[2]); r[7] = f2h(b[3]);
    return r;
}

// ---------------------------------------------------------------------------
// Tiled "DMA-order" layout (R5-verified): matrix [M][2048] stored as 16x32
// tiles, tile T = (row/16)*64 + (col/32), 1KB contiguous; slot
// s = ((col>>3)&3)*16 + (row&15). One g2l16 of a tile = contiguous 1KB read,
// LDS image is fragment-major (lane l's MFMA fragment = slot l, 0 conflicts).
// ---------------------------------------------------------------------------
__global__ __launch_bounds__(256) void cvt4(
    const float* __restrict__ hs, const float* __restrict__ Wq,
    const float* __restrict__ Wk, const float* __restrict__ Wv,
    u16* __restrict__ hs16, u16* __restrict__ wq16,
    u16* __restrict__ wk16, u16* __restrict__ wv16)
{
    int blk = blockIdx.x;
    const float* s; u16* d;
    if (blk < 4096)      { s = hs; d = hs16; }
    else if (blk < 6144) { s = Wq; d = wq16; blk -= 4096; }
    else if (blk < 8192) { s = Wk; d = wk16; blk -= 6144; }
    else                 { s = Wv; d = wv16; blk -= 8192; }
    const int R = blk >> 4, slab = blk & 15;
    const int t = threadIdx.x;
    const int row = R * 16 + (t >> 4);
    const int col = slab * 128 + (t & 15) * 8;
    u16x8 v = ld8f(s + (size_t)row * 2048 + col);
    const size_t o = ((size_t)(R * 64 + slab * 4 + ((t >> 2) & 3))) * 512
                   + ((t & 3) * 16 + (t >> 4)) * 8;
    *(u16x8*)(d + o) = v;
}

__global__ __launch_bounds__(256) void cvt1(const float* __restrict__ s, u16* __restrict__ d) {
    const int blk = blockIdx.x;
    const int R = blk >> 4, slab = blk & 15;
    const int t = threadIdx.x;
    const int row = R * 16 + (t >> 4);
    const int col = slab * 128 + (t & 15) * 8;
    u16x8 v = ld8f(s + (size_t)row * 2048 + col);
    const size_t o = ((size_t)(R * 64 + slab * 4 + ((t >> 2) & 3))) * 512
                   + ((t & 3) * 16 + (t >> 4)) * 8;
    *(u16x8*)(d + o) = v;
}

// ---------------------------------------------------------------------------
// QKV GEMM v5: 256x128 tile, 8 waves (2M x 4N), BK=32, 3-deep buffers,
// 2-phase K-step with counted vmcnt (never 0 in steady state).
// Per wave: 128x32 output = acc[8][2] f32x4. Per K-step per wave: 16 MFMA,
// 10 ds_read_b128, 3 g2l16 (2 A-tiles + 1 B-tile staged for step t+2).
// Phase: {stage || ds_read} -> barrier -> lgkmcnt(0) -> 8 MFMA -> barrier.
// z=0->Q, 1->K ([b*s][h*d] row-major); z=2->V^T [b,h,d,s].
// ---------------------------------------------------------------------------
__global__ __launch_bounds__(512, 4) void gemm_qkv(
    const u16* __restrict__ A,
    const u16* __restrict__ W0, const u16* __restrict__ W1, const u16* __restrict__ W2,
    const float* __restrict__ B0, const float* __restrict__ B1, const float* __restrict__ B2,
    u16* __restrict__ Cq, u16* __restrict__ Ck, u16* __restrict__ Cvt)
{
    constexpr int N = 2048, NT = 64;
    const int z = blockIdx.z;
    const u16* W      = (z == 0) ? W0 : ((z == 1) ? W1 : W2);
    const float* bias = (z == 0) ? B0 : ((z == 1) ? B1 : B2);
    const int m0 = blockIdx.y * 256, n0 = blockIdx.x * 128;

    // 3 bufs x (16 A-tiles + 8 B-tiles) x 512 u16 = 72 KB -> 2 blocks/CU
    __shared__ __attribute__((aligned(16))) u16 Ls[3][24 * 512];

    const int tid = threadIdx.x, l = tid & 63, w = tid >> 6;   // w 0..7
    const int quad = l >> 4, lan = l & 15;
    const int wm = w >> 2, wn = w & 3;

    // staging: wave w owns A row-groups {2w, 2w+1} and B n-group {w}
    const u16* sA0 = A + ((size_t)((m0 >> 4) + 2 * w) * 64) * 512 + l * 8;
    const u16* sA1 = A + ((size_t)((m0 >> 4) + 2 * w + 1) * 64) * 512 + l * 8;
    const u16* sB0 = W + ((size_t)((n0 >> 4) + w) * 64) * 512 + l * 8;
    const int dA0 = (2 * w) * 512, dA1 = (2 * w + 1) * 512, dB = (16 + w) * 512;

    f32x4 acc[8][2] = {};

    // prologue: stage K-steps 0 and 1; own-wave oldest-3 (step 0) must land
    g2l16(sA0, &Ls[0][dA0]); g2l16(sA1, &Ls[0][dA1]); g2l16(sB0, &Ls[0][dB]);
    g2l16(sA0 + 512, &Ls[1][dA0]); g2l16(sA1 + 512, &Ls[1][dA1]); g2l16(sB0 + 512, &Ls[1][dB]);
    __asm__ volatile("s_waitcnt vmcnt(3)" ::: "memory");
    __builtin_amdgcn_s_barrier();
    __builtin_amdgcn_sched_barrier(0);

    int bc = 0;
    for (int t = 0; t < NT; ++t) {
        int bs = bc + 2; if (bs >= 3) bs -= 3;       // buffer of step t+2
        const u16* Lb = Ls[bc];

        // ---- phase 0: stage A(t+2) || read A-frags 0..3 + both B-frags
        if (t + 2 < NT) {
            const int kk = (t + 2) * 512;
            g2l16(sA0 + kk, &Ls[bs][dA0]);
            g2l16(sA1 + kk, &Ls[bs][dA1]);
        }
        f16x8 bf0 = __builtin_bit_cast(f16x8, *(const u16x8*)(&Lb[(16 + wn * 2) * 512 + l * 8]));
        f16x8 bf1 = __builtin_bit_cast(f16x8, *(const u16x8*)(&Lb[(17 + wn * 2) * 512 + l * 8]));
        f16x8 af[4];
#pragma unroll
        for (int i = 0; i < 4; i++)
            af[i] = __builtin_bit_cast(f16x8, *(const u16x8*)(&Lb[(wm * 8 + i) * 512 + l * 8]));
        __builtin_amdgcn_s_barrier();
        __asm__ volatile("s_waitcnt lgkmcnt(0)" ::: "memory");
        __builtin_amdgcn_sched_barrier(0);
        __builtin_amdgcn_s_setprio(1);
#pragma unroll
        for (int i = 0; i < 4; i++) {
            acc[i][0] = __builtin_amdgcn_mfma_f32_16x16x32_f16(af[i], bf0, acc[i][0], 0, 0, 0);
            acc[i][1] = __builtin_amdgcn_mfma_f32_16x16x32_f16(af[i], bf1, acc[i][1], 0, 0, 0);
        }
        __builtin_amdgcn_s_setprio(0);
        __builtin_amdgcn_s_barrier();

        // ---- phase 1: stage B(t+2) || read A-frags 4..7
        if (t + 2 < NT) {
            const int kk = (t + 2) * 512;
            g2l16(sB0 + kk, &Ls[bs][dB]);
        }
#pragma unroll
        for (int i = 0; i < 4; i++)
            af[i] = __builtin_bit_cast(f16x8, *(const u16x8*)(&Lb[(wm * 8 + 4 + i) * 512 + l * 8]));
        __builtin_amdgcn_s_barrier();
        __asm__ volatile("s_waitcnt lgkmcnt(0)" ::: "memory");
        __builtin_amdgcn_sched_barrier(0);
        __builtin_amdgcn_s_setprio(1);
#pragma unroll
        for (int i = 0; i < 4; i++) {
            acc[4 + i][0] = __builtin_amdgcn_mfma_f32_16x16x32_f16(af[i], bf0, acc[4 + i][0], 0, 0, 0);
            acc[4 + i][1] = __builtin_amdgcn_mfma_f32_16x16x32_f16(af[i], bf1, acc[4 + i][1], 0, 0, 0);
        }
        __builtin_amdgcn_s_setprio(0);

        // end-of-step: own t-1 stages (for t+1) must land; t's 3 stay in flight
        if (t + 2 < NT) { __asm__ volatile("s_waitcnt vmcnt(3)" ::: "memory"); }
        else            { __asm__ volatile("s_waitcnt vmcnt(0)" ::: "memory"); }
        __builtin_amdgcn_s_barrier();
        __builtin_amdgcn_sched_barrier(0);
        bc = (bc == 2) ? 0 : bc + 1;
    }

    if (z < 2) {
        u16* C = (z == 0) ? Cq : Ck;
#pragma unroll
        for (int j = 0; j < 2; j++) {
            const int col = n0 + wn * 32 + j * 16 + lan;
            const float bj = bias[col];
#pragma unroll
            for (int i = 0; i < 8; i++)
#pragma unroll
                for (int r = 0; r < 4; r++) {
                    const int row = m0 + wm * 128 + i * 16 + quad * 4 + r;
                    C[(size_t)row * N + col] = f2h(acc[i][j][r] + bj);
                }
        }
    } else {
        // V transposed: row=(b,s), col=(h,d) -> Cvt[((b*16+h)*128+d)*2048 + s]
#pragma unroll
        for (int j = 0; j < 2; j++) {
            const int col = n0 + wn * 32 + j * 16 + lan;
            const int hh = col >> 7, dd = col & 127;
            const float bj = bias[col];
            u16* Cr = Cvt + ((size_t)hh * 128 + dd) * 2048;
#pragma unroll
            for (int i = 0; i < 8; i++) {
                const int row0 = m0 + wm * 128 + i * 16 + quad * 4;
                const int bb = row0 >> 11, ss = row0 & 2047;
                u16x4 pv;
#pragma unroll
                for (int r = 0; r < 4; r++) pv[r] = f2h(acc[i][j][r] + bj);
                *(u16x4*)(Cr + (size_t)bb * 4194304 + ss) = pv;
            }
        }
    }
}

// ---------------------------------------------------------------------------
// RMSNorm + RoPE + history key scale; in-place f16 q/k; q *= 1/sqrt(128).
// ---------------------------------------------------------------------------
__global__ __launch_bounds__(256) void norm_rope(
    u16* __restrict__ q, u16* __restrict__ k,
    const float* __restrict__ rot,
    const float* __restrict__ nqw, const float* __restrict__ nkw,
    const float* __restrict__ hks, const int* __restrict__ oclp)
{
    const int row = blockIdx.x;
    const int s = row & 2047;
    const int t = threadIdx.x;
    const size_t base = (size_t)row * 2048 + t * 8;

    u16x8 q8 = *(const u16x8*)(q + base);
    u16x8 k8 = *(const u16x8*)(k + base);

    float qf[8], kf[8];
    float sq = 0.f, sk = 0.f;
#pragma unroll
    for (int i = 0; i < 8; i++) {
        qf[i] = h2f(q8[i]); sq += qf[i] * qf[i];
        kf[i] = h2f(k8[i]); sk += kf[i] * kf[i];
    }
#pragma unroll
    for (int off = 32; off > 0; off >>= 1) {
        sq += __shfl_down(sq, off);
        sk += __shfl_down(sk, off);
    }
    __shared__ float rq[4], rk[4];
    const int wv = t >> 6;
    if ((t & 63) == 0) { rq[wv] = sq; rk[wv] = sk; }
    __syncthreads();
    const float tq = rq[0] + rq[1] + rq[2] + rq[3];
    const float tk = rk[0] + rk[1] + rk[2] + rk[3];
    const float scq = rsqrtf(tq * (1.0f / 2048.0f) + 1e-5f);
    const float sck = rsqrtf(tk * (1.0f / 2048.0f) + 1e-5f);
#pragma unroll
    for (int i = 0; i < 8; i++) {
        qf[i] *= scq * nqw[t * 8 + i];
        kf[i] *= sck * nkw[t * 8 + i];
    }
    const int e0 = t * 8;
    const int dh0 = e0 & 127;
    const int h = e0 >> 7;
    float qo[8], ko[8];
#pragma unroll
    for (int p = 0; p < 4; p++) {
        const int dh = dh0 + 2 * p;
        const float c  = rot[s * 256 + dh];
        const float sn = rot[s * 256 + 128 + dh + 1];
        qo[2 * p]     = qf[2 * p] * c  - qf[2 * p + 1] * sn;
        qo[2 * p + 1] = qf[2 * p] * sn + qf[2 * p + 1] * c;
        ko[2 * p]     = kf[2 * p] * c  - kf[2 * p + 1] * sn;
        ko[2 * p + 1] = kf[2 * p] * sn + kf[2 * p + 1] * c;
    }
    const float ATT = 0.08838834764831845f;
#pragma unroll
    for (int i = 0; i < 8; i++) qo[i] *= ATT;

    const int hist = 2048 - oclp[0];
    if (s < hist) {
        const float hv = hks[h];
        const float scl = 1.0f + 9.0f / (1.0f + expf(-hv));
#pragma unroll
        for (int i = 0; i < 8; i++) ko[i] *= scl;
    }

    u16x8 qo8, ko8;
#pragma unroll
    for (int i = 0; i < 8; i++) { qo8[i] = f2h(qo[i]); ko8[i] = f2h(ko[i]); }
    *(u16x8*)(q + base) = qo8;
    *(u16x8*)(k + base) = ko8;
}

// ---------------------------------------------------------------------------
// Flash attention v8 (R5-verified) + defer-max THR 4->8 (T13, HK value).
// ---------------------------------------------------------------------------
__global__ __launch_bounds__(256, 4) void flash_attn8(
    const u16* __restrict__ Q, const u16* __restrict__ Kr, const u16* __restrict__ Vt,
    u16* __restrict__ O)
{
    const int qt = blockIdx.x;        // 0..15 (128 q-rows each)
    const int bh = blockIdx.y;        // 0..31
    const int b = bh >> 4, h = bh & 15;
    const int tid = threadIdx.x, l = tid & 63, w = tid >> 6;
    const int quad = l >> 4, lan = l & 15;

    __shared__ __attribute__((aligned(16))) u16 Kb[2][32 * 128];
    __shared__ __attribute__((aligned(16))) u16 VTb[2][128 * 32];
    __shared__ __attribute__((aligned(16))) u16 Pb[4][32 * 40];

    // Q frags for both q-groups (rows w*32 + g*16 + lan); pre-scaled by ATT
    f16x8 qf0[4], qf1[4];
    {
        const u16* qp = Q + ((size_t)(b * 2048 + qt * 128 + w * 32 + lan)) * 2048 + h * 128 + quad * 8;
#pragma unroll
        for (int ks = 0; ks < 4; ks++) {
            qf0[ks] = __builtin_bit_cast(f16x8, *(const u16x8*)(qp + ks * 32));
            qf1[ks] = __builtin_bit_cast(f16x8, *(const u16x8*)(qp + 16 * 2048 + ks * 32));
        }
    }

    const int krow_b = w * 4 + (l >> 4);
    const int kchk   = l & 15;
    const u16* kbase = Kr + ((size_t)(b * 2048)) * 2048 + h * 128;
    const int vrow_b = w * 16 + (l >> 2);
    const int vg     = ((l & 3) ^ ((l >> 3) & 3)) * 8;
    const u16* vbase = Vt + ((size_t)((b * 16 + h) * 128)) * 2048;

    float mr0 = -3.0e38f, lrp0 = 0.f;
    float mr1 = -3.0e38f, lrp1 = 0.f;
    f32x4 o0[8] = {}, o1[8] = {};

    // issue DMA for tile 0 into buf 0
#pragma unroll
    for (int i = 0; i < 2; i++) {
        const int kr = krow_b + 16 * i;
        g2l16(kbase + (size_t)kr * 2048 + ((kchk ^ (kr & 15)) * 8), &Kb[0][(w * 64 + 256 * i) * 8]);
    }
#pragma unroll
    for (int i = 0; i < 2; i++) {
        const int vr = vrow_b + 64 * i;
        g2l16(vbase + (size_t)vr * 2048 + vg, &VTb[0][(w * 64 + 256 * i) * 8]);
    }
    __syncthreads();   // drain tile-0 DMA

    for (int kt = 0; kt < 64; kt++) {
        const int buf = kt & 1;
        if (kt < 63) {
            const int kn = (kt + 1) * 32;
#pragma unroll
            for (int i = 0; i < 2; i++) {
                const int kr = krow_b + 16 * i;
                g2l16(kbase + (size_t)(kn + kr) * 2048 + ((kchk ^ (kr & 15)) * 8),
                      &Kb[buf ^ 1][(w * 64 + 256 * i) * 8]);
            }
#pragma unroll
            for (int i = 0; i < 2; i++) {
                const int vr = vrow_b + 64 * i;
                g2l16(vbase + (size_t)vr * 2048 + kn + vg,
                      &VTb[buf ^ 1][(w * 64 + 256 * i) * 8]);
            }
        }

        // S^T = K Q^T : kb read once, used for BOTH q-groups
        f32x4 s0[2] = {}, s1[2] = {};
        __builtin_amdgcn_s_setprio(1);
#pragma unroll
        for (int ks = 0; ks < 4; ks++)
#pragma unroll
            for (int nt = 0; nt < 2; nt++) {
                f16x8 kb = __builtin_bit_cast(f16x8, *(const u16x8*)(
                    &Kb[buf][(nt * 16 + lan) * 128 + (((ks * 4 + quad) ^ lan) * 8)]));
                s0[nt] = __builtin_amdgcn_mfma_f32_16x16x32_f16(kb, qf0[ks], s0[nt], 0, 0, 0);
                s1[nt] = __builtin_amdgcn_mfma_f32_16x16x32_f16(kb, qf1[ks], s1[nt], 0, 0, 0);
            }
        __builtin_amdgcn_s_setprio(0);

        // per-lane scalar online softmax, per q-group
        float tm0 = fmaxf(fmaxf(fmaxf(s0[0][0], s0[0][1]), fmaxf(s0[0][2], s0[0][3])),
                          fmaxf(fmaxf(s0[1][0], s0[1][1]), fmaxf(s0[1][2], s0[1][3])));
        float tm1 = fmaxf(fmaxf(fmaxf(s1[0][0], s1[0][1]), fmaxf(s1[0][2], s1[0][3])),
                          fmaxf(fmaxf(s1[1][0], s1[1][1]), fmaxf(s1[1][2], s1[1][3])));
        tm0 = fmaxf(tm0, __shfl_xor(tm0, 16)); tm0 = fmaxf(tm0, __shfl_xor(tm0, 32));
        tm1 = fmaxf(tm1, __shfl_xor(tm1, 16)); tm1 = fmaxf(tm1, __shfl_xor(tm1, 32));

        if (!__all(tm0 <= mr0 + 8.0f)) {
            const float nm = fmaxf(mr0, tm0);
            const float al = exp2f((mr0 - nm) * LOG2E);
            mr0 = nm; lrp0 *= al;
#pragma unroll
            for (int nd = 0; nd < 8; nd++)
#pragma unroll
                for (int r = 0; r < 4; r++) o0[nd][r] *= al;
        }
        if (!__all(tm1 <= mr1 + 8.0f)) {
            const float nm = fmaxf(mr1, tm1);
            const float al = exp2f((mr1 - nm) * LOG2E);
            mr1 = nm; lrp1 *= al;
#pragma unroll
            for (int nd = 0; nd < 8; nd++)
#pragma unroll
                for (int r = 0; r < 4; r++) o1[nd][r] *= al;
        }

        float ps0 = 0.f, ps1 = 0.f;
        u16x4 a0, a1, b0, b1;
#pragma unroll
        for (int r = 0; r < 4; r++) {
            float p = exp2f((s0[0][r] - mr0) * LOG2E); ps0 += p; a0[r] = f2h(p);
            p = exp2f((s0[1][r] - mr0) * LOG2E);       ps0 += p; a1[r] = f2h(p);
            p = exp2f((s1[0][r] - mr1) * LOG2E);       ps1 += p; b0[r] = f2h(p);
            p = exp2f((s1[1][r] - mr1) * LOG2E);       ps1 += p; b1[r] = f2h(p);
        }
        lrp0 += ps0; lrp1 += ps1;

        *(u16x4*)(&Pb[w][lan * 40 + quad * 4])             = a0;
        *(u16x4*)(&Pb[w][lan * 40 + 16 + quad * 4])        = a1;
        *(u16x4*)(&Pb[w][(16 + lan) * 40 + quad * 4])      = b0;
        *(u16x4*)(&Pb[w][(16 + lan) * 40 + 16 + quad * 4]) = b1;

        __asm__ volatile("s_waitcnt lgkmcnt(0)" ::: "memory");  // own-wave P visible

        f16x8 pf0 = __builtin_bit_cast(f16x8, *(const u16x8*)(&Pb[w][lan * 40 + quad * 8]));
        f16x8 pf1 = __builtin_bit_cast(f16x8, *(const u16x8*)(&Pb[w][(16 + lan) * 40 + quad * 8]));
        __builtin_amdgcn_s_setprio(1);
#pragma unroll
        for (int nd = 0; nd < 8; nd++) {
            f16x8 vtf = __builtin_bit_cast(f16x8, *(const u16x8*)(
                &VTb[buf][(nd * 16 + lan) * 32 + ((quad ^ ((lan >> 1) & 3)) * 8)]));
            o0[nd] = __builtin_amdgcn_mfma_f32_16x16x32_f16(vtf, pf0, o0[nd], 0, 0, 0);
            o1[nd] = __builtin_amdgcn_mfma_f32_16x16x32_f16(vtf, pf1, o1[nd], 0, 0, 0);
        }
        __builtin_amdgcn_s_setprio(0);

        __syncthreads();   // drains kt+1 DMA (had full compute to land) + syncs
    }

    lrp0 += __shfl_xor(lrp0, 16); lrp0 += __shfl_xor(lrp0, 32);
    lrp1 += __shfl_xor(lrp1, 16); lrp1 += __shfl_xor(lrp1, 32);
    const float inv0 = 1.0f / lrp0;
    const float inv1 = 1.0f / lrp1;

    // TILED aout epilogue (R5-verified)
    const int Rb = b * 128 + qt * 8 + w * 2;
#pragma unroll
    for (int nd = 0; nd < 8; nd++) {
        u16x4 ov;
#pragma unroll
        for (int r = 0; r < 4; r++) ov[r] = f2h(o0[nd][r] * inv0);
        const size_t off = ((size_t)(Rb * 64 + h * 4 + (nd >> 1))) * 512
                         + (((nd & 1) * 2 + (quad >> 1)) * 16 + lan) * 8 + (quad & 1) * 4;
        *(u16x4*)(O + off) = ov;
    }
#pragma unroll
    for (int nd = 0; nd < 8; nd++) {
        u16x4 ov;
#pragma unroll
        for (int r = 0; r < 4; r++) ov[r] = f2h(o1[nd][r] * inv1);
        const size_t off = ((size_t)((Rb + 1) * 64 + h * 4 + (nd >> 1))) * 512
                         + (((nd & 1) * 2 + (quad >> 1)) * 16 + lan) * 8 + (quad & 1) * 4;
        *(u16x4*)(O + off) = ov;
    }
}

// ---------------------------------------------------------------------------
// Output projection v5: same 256x128 / 8-wave / 2-phase counted-vmcnt GEMM.
// A = aout (tiled) f16, B = Wo16 (tiled) f16, C fp32 row-major.
// ---------------------------------------------------------------------------
__global__ __launch_bounds__(512, 4) void gemm_out(
    const u16* __restrict__ A, const u16* __restrict__ W,
    const float* __restrict__ bias, float* __restrict__ C)
{
    constexpr int N = 2048, NT = 64;
    const int m0 = blockIdx.y * 256, n0 = blockIdx.x * 128;

    __shared__ __attribute__((aligned(16))) u16 Ls[3][24 * 512];

    const int tid = threadIdx.x, l = tid & 63, w = tid >> 6;
    const int quad = l >> 4, lan = l & 15;
    const int wm = w >> 2, wn = w & 3;

    const u16* sA0 = A + ((size_t)((m0 >> 4) + 2 * w) * 64) * 512 + l * 8;
    const u16* sA1 = A + ((size_t)((m0 >> 4) + 2 * w + 1) * 64) * 512 + l * 8;
    const u16* sB0 = W + ((size_t)((n0 >> 4) + w) * 64) * 512 + l * 8;
    const int dA0 = (2 * w) * 512, dA1 = (2 * w + 1) * 512, dB = (16 + w) * 512;

    f32x4 acc[8][2] = {};

    g2l16(sA0, &Ls[0][dA0]); g2l16(sA1, &Ls[0][dA1]); g2l16(sB0, &Ls[0][dB]);
    g2l16(sA0 + 512, &Ls[1][dA0]); g2l16(sA1 + 512, &Ls[1][dA1]); g2l16(sB0 + 512, &Ls[1][dB]);
    __asm__ volatile("s_waitcnt vmcnt(3)" ::: "memory");
    __builtin_amdgcn_s_barrier();
    __builtin_amdgcn_sched_barrier(0);

    int bc = 0;
    for (int t = 0; t < NT; ++t) {
        int bs = bc + 2; if (bs >= 3) bs -= 3;
        const u16* Lb = Ls[bc];

        if (t + 2 < NT) {
            const int kk = (t + 2) * 512;
            g2l16(sA0 + kk, &Ls[bs][dA0]);
            g2l16(sA1 + kk, &Ls[bs][dA1]);
        }
        f16x8 bf0 = __builtin_bit_cast(f16x8, *(const u16x8*)(&Lb[(16 + wn * 2) * 512 + l * 8]));
        f16x8 bf1 = __builtin_bit_cast(f16x8, *(const u16x8*)(&Lb[(17 + wn * 2) * 512 + l * 8]));
        f16x8 af[4];
#pragma unroll
        for (int i = 0; i < 4; i++)
            af[i] = __builtin_bit_cast(f16x8, *(const u16x8*)(&Lb[(wm * 8 + i) * 512 + l * 8]));
        __builtin_amdgcn_s_barrier();
        __asm__ volatile("s_waitcnt lgkmcnt(0)" ::: "memory");
        __builtin_amdgcn_sched_barrier(0);
        __builtin_amdgcn_s_setprio(1);
#pragma unroll
        for (int i = 0; i < 4; i++) {
            acc[i][0] = __builtin_amdgcn_mfma_f32_16x16x32_f16(af[i], bf0, acc[i][0], 0, 0, 0);
            acc[i][1] = __builtin_amdgcn_mfma_f32_16x16x32_f16(af[i], bf1, acc[i][1], 0, 0, 0);
        }
        __builtin_amdgcn_s_setprio(0);
        __builtin_amdgcn_s_barrier();

        if (t + 2 < NT) {
            const int kk = (t + 2) * 512;
            g2l16(sB0 + kk, &Ls[bs][dB]);
        }
#pragma unroll
        for (int i = 0; i < 4; i++)
            af[i] = __builtin_bit_cast(f16x8, *(const u16x8*)(&Lb[(wm * 8 + 4 + i) * 512 + l * 8]));
        __builtin_amdgcn_s_barrier();
        __asm__ volatile("s_waitcnt lgkmcnt(0)" ::: "memory");
        __builtin_amdgcn_sched_barrier(0);
        __builtin_amdgcn_s_setprio(1);
#pragma unroll
        for (int i = 0; i < 4; i++) {
            acc[4 + i][0] = __builtin_amdgcn_mfma_f32_16x16x32_f16(af[i], bf0, acc[4 + i][0], 0, 0, 0);
            acc[4 + i][1] = __builtin_amdgcn_mfma_f32_16x16x32_f16(af[i], bf1, acc[4 + i][1], 0, 0, 0);
        }
        __builtin_amdgcn_s_setprio(0);

        if (t + 2 < NT) { __asm__ volatile("s_waitcnt vmcnt(3)" ::: "memory"); }
        else            { __asm__ volatile("s_waitcnt vmcnt(0)" ::: "memory"); }
        __builtin_amdgcn_s_barrier();
        __builtin_amdgcn_sched_barrier(0);
        bc = (bc == 2) ? 0 : bc + 1;
    }

#pragma unroll
    for (int j = 0; j < 2; j++) {
        const int col = n0 + wn * 32 + j * 16 + lan;
        const float bj = bias[col];
#pragma unroll
        for (int i = 0; i < 8; i++)
#pragma unroll
            for (int r = 0; r < 4; r++) {
                const int row = m0 + wm * 128 + i * 16 + quad * 4 + r;
                C[(size_t)row * N + col] = acc[i][j][r] + bj;
            }
    }
}

// ---------------------------------------------------------------------------
extern "C" void kernel_launch(void* const* d_in, const int* in_sizes, int n_in,
                              void* d_out, int out_size, void* d_ws, size_t ws_size,
                              hipStream_t stream) {
    const float* hs  = (const float*)d_in[0];
    const float* rot = (const float*)d_in[1];
    const float* Wq  = (const float*)d_in[2];
    const float* bq  = (const float*)d_in[3];
    const float* Wk  = (const float*)d_in[4];
    const float* bk  = (const float*)d_in[5];
    const float* Wv  = (const float*)d_in[6];
    const float* bv  = (const float*)d_in[7];
    const float* nqw = (const float*)d_in[8];
    const float* nkw = (const float*)d_in[9];
    const float* hks = (const float*)d_in[10];
    const float* Wo  = (const float*)d_in[11];
    const float* bo  = (const float*)d_in[12];
    const int*   ocl = (const int*)d_in[13];

    // ws (64 MiB): [0:16) qraw | [16:32) kraw | [32:48) vtr | [48:64) aout
    u16* qraw = (u16*)d_ws;
    u16* kraw = qraw + 8388608;
    u16* vtr  = kraw + 8388608;
    u16* aout = vtr + 8388608;
    u16* wq16 = aout;                  // [48:56 MiB)
    u16* wk16 = aout + 4194304;        // [56:64 MiB)
    u16* wo16 = qraw;                  // reuses qraw AFTER flash
    float* out = (float*)d_out;
    u16* hs16 = (u16*)d_out;           // d_out [0:16 MiB)
    u16* wv16 = hs16 + 8388608;        // d_out [16:24 MiB)

    // 0) convert hs + Wq/Wk/Wv to f16 (TILED layout)
    cvt4<<<dim3(10240), 256, 0, stream>>>(hs, Wq, Wk, Wv, hs16, wq16, wk16, wv16);
    // 1) QKV projection (256x128 8-wave 2-phase); z=2 writes V^T
    gemm_qkv<<<dim3(16, 16, 3), 512, 0, stream>>>(
        hs16, wq16, wk16, wv16, bq, bk, bv, qraw, kraw, vtr);
    // 2) rmsnorm + rope + history scale
    norm_rope<<<dim3(4096), 256, 0, stream>>>(qraw, kraw, rot, nqw, nkw, hks, ocl);
    // 3) flash attention v8 (THR=8) -> aout (tiled)
    flash_attn8<<<dim3(16, 32), 256, 0, stream>>>(qraw, kraw, vtr, aout);
    // 4) Wo -> f16 (tiled), then output projection (256x128 8-wave) -> d_out
    cvt1<<<dim3(2048), 256, 0, stream>>>(Wo, wo16);
    gemm_out<<<dim3(16, 16), 512, 0, stream>>>(aout, wo16, bo, out);
}